// Round 6
// baseline (168.370 us; speedup 1.0000x reference)
//
#include <hip/hip_runtime.h>

#define IMH 512
#define IMW 512
#define NPIX (IMH * IMW)
#define RS 516                 // padded row stride (floats)
#define PR 514                 // padded rows (1-px zero border, interior origin (1,1))
#define PLANE (PR * RS)        // floats per plane
#define NCH 30                 // planes: 0..2 = Z, 3+ij*3+s = w_pre(s,ij)
#define NBORD 2052             // border cells per plane: 2*514 + 2*512

// ---------------- Kernel 1: pointwise Bayes update + sensitivity -> planar ws
// (unchanged from R5: stores are lane-consecutive dwords = perfectly coalesced)
__global__ __launch_bounds__(256)
void k1_pointwise(const float* __restrict__ obs,
                  const float* __restrict__ P,     // P[o*3+s]
                  const float* __restrict__ u_k,
                  const float* __restrict__ w_k,   // pix*27 + s*9 + ij
                  float* __restrict__ ws) {
    const int gtid = blockIdx.x * 256 + threadIdx.x;   // 0..NPIX-1

    // zero the 1-px borders of all 30 planes (disjoint from interior writes)
    for (int i = gtid; i < NCH * NBORD; i += NPIX) {
        const int pl = i / NBORD, r = i - pl * NBORD;
        int rr, cc;
        if (r < 514)       { rr = 0;            cc = r; }
        else if (r < 1028) { rr = 513;          cc = r - 514; }
        else if (r < 1540) { rr = r - 1028 + 1; cc = 0; }
        else               { rr = r - 1540 + 1; cc = 513; }
        ws[(size_t)pl * PLANE + rr * RS + cc] = 0.0f;
    }

    const int h = gtid >> 9, w = gtid & 511;
    const float ov[3] = {obs[gtid*3+0], obs[gtid*3+1], obs[gtid*3+2]};
    const float us[3] = {u_k[gtid*3+0], u_k[gtid*3+1], u_k[gtid*3+2]};

    float b[3], Bu[3], bu = 0.0f;
#pragma unroll
    for (int s = 0; s < 3; ++s) {
        b[s] = P[s] * ov[0] + P[3+s] * ov[1] + P[6+s] * ov[2];
        Bu[s] = b[s] * us[s];
        bu += Bu[s];
    }
    const float inv_bu = 1.0f / bu;
    float Z[3];
#pragma unroll
    for (int s = 0; s < 3; ++s) Z[s] = Bu[s] * inv_bu;

    const int base = (h + 1) * RS + (w + 1);
    ws[0*PLANE + base] = Z[0];
    ws[1*PLANE + base] = Z[1];
    ws[2*PLANE + base] = Z[2];

    const float* wk = w_k + (size_t)gtid * 27;
    float wv[27];
#pragma unroll
    for (int c = 0; c < 27; ++c) wv[c] = wk[c];   // 27 independent loads (MLP)

#pragma unroll
    for (int ij = 0; ij < 9; ++ij) {
        const int i = ij / 3, j = ij % 3;
        float du[3], sdu = 0.0f;
#pragma unroll
        for (int s = 0; s < 3; ++s) {
            float d = b[s] * wv[s*9 + ij];
            if (s == j) d += ov[i] * us[s];
            du[s] = d;
            sdu += d;
        }
#pragma unroll
        for (int s = 0; s < 3; ++s)
            ws[(size_t)(3 + ij*3 + s) * PLANE + base] = (du[s] - sdu * Z[s]) * inv_bu;
    }
}

// ---------------- Kernel 2: role-split 3x3 conv + softmax + softmax-JVP
// gridDim.y = 5 roles (block-uniform -> no divergence):
//   role 0   : group0 (softmax -> u) + tangent ij0
//   role 1..4: group0 (recomputed, bit-identical p) + tangents ij(2r-1), ij(2r)
// Tap loop is ROLLED so only 9 weights (uniform s_loads) + 9 values + 9 accs
// are live -> low VGPR -> high occupancy. Plane bases are wave-uniform (SGPR).
__global__ __launch_bounds__(256, 5)
void k2_conv_roles(const float* __restrict__ ws,
                   const float* __restrict__ conv_w,   // (S_out,S_in,3,3)
                   const float* __restrict__ conv_b,
                   float* __restrict__ out) {
    const int px = blockIdx.x * 256 + threadIdx.x;   // 0..NPIX-1
    const int role = blockIdx.y;                     // 0..4
    const int h = px >> 9, w = px & 511;
    const int base = h * RS + w;                     // window top-left in padded plane

    const int ija = (role == 0) ? 0 : (2 * role - 1);
    const int ijb = 2 * role;                        // used only when role>0

    const float* pZ = ws + base;                             // planes 0..2
    const float* pA = ws + (size_t)(3 + 3 * ija) * PLANE + base;
    const float* pB = ws + (size_t)(3 + 3 * ijb) * PLANE + base;

    float y0 = 0.f, y1 = 0.f, y2 = 0.f;
    float A0 = 0.f, A1 = 0.f, A2 = 0.f;
    float B0 = 0.f, B1 = 0.f, B2 = 0.f;

#pragma unroll 1
    for (int ky = 0; ky < 3; ++ky) {
#pragma unroll 1
        for (int kx = 0; kx < 3; ++kx) {
            const int off = ky * RS + kx;
            const int tap = ky * 3 + kx;
            // 9 weights for this tap (uniform -> scalar loads, K$-hot)
            const float w00 = conv_w[ 0 + tap], w01 = conv_w[ 9 + tap], w02 = conv_w[18 + tap];
            const float w10 = conv_w[27 + tap], w11 = conv_w[36 + tap], w12 = conv_w[45 + tap];
            const float w20 = conv_w[54 + tap], w21 = conv_w[63 + tap], w22 = conv_w[72 + tap];
            {
                const float v0 = pZ[off], v1 = pZ[PLANE + off], v2 = pZ[2*PLANE + off];
                y0 += w00*v0 + w01*v1 + w02*v2;
                y1 += w10*v0 + w11*v1 + w12*v2;
                y2 += w20*v0 + w21*v1 + w22*v2;
            }
            {
                const float v0 = pA[off], v1 = pA[PLANE + off], v2 = pA[2*PLANE + off];
                A0 += w00*v0 + w01*v1 + w02*v2;
                A1 += w10*v0 + w11*v1 + w12*v2;
                A2 += w20*v0 + w21*v1 + w22*v2;
            }
            if (role != 0) {
                const float v0 = pB[off], v1 = pB[PLANE + off], v2 = pB[2*PLANE + off];
                B0 += w00*v0 + w01*v1 + w02*v2;
                B1 += w10*v0 + w11*v1 + w12*v2;
                B2 += w20*v0 + w21*v1 + w22*v2;
            }
        }
    }

    // softmax on group 0 (identical arithmetic in every role -> identical p)
    y0 += conv_b[0]; y1 += conv_b[1]; y2 += conv_b[2];
    const float m = fmaxf(y0, fmaxf(y1, y2));
    const float e0 = __expf(y0 - m), e1 = __expf(y1 - m), e2 = __expf(y2 - m);
    const float inv = 1.0f / (e0 + e1 + e2);
    const float p0 = e0 * inv, p1 = e1 * inv, p2 = e2 * inv;

    float* outw = out + (size_t)NPIX * 3 + (size_t)px * 27;  // + s*9 + ij
    {
        const float dotA = p0*A0 + p1*A1 + p2*A2;
        outw[ 0 + ija] = p0 * (A0 - dotA);
        outw[ 9 + ija] = p1 * (A1 - dotA);
        outw[18 + ija] = p2 * (A2 - dotA);
    }
    if (role != 0) {
        const float dotB = p0*B0 + p1*B1 + p2*B2;
        outw[ 0 + ijb] = p0 * (B0 - dotB);
        outw[ 9 + ijb] = p1 * (B1 - dotB);
        outw[18 + ijb] = p2 * (B2 - dotB);
    } else {
        out[px*3 + 0] = p0;
        out[px*3 + 1] = p1;
        out[px*3 + 2] = p2;
    }
}

extern "C" void kernel_launch(void* const* d_in, const int* in_sizes, int n_in,
                              void* d_out, int out_size, void* d_ws, size_t ws_size,
                              hipStream_t stream) {
    const float* obs    = (const float*)d_in[0];
    const float* P      = (const float*)d_in[1];
    const float* u_k    = (const float*)d_in[2];
    const float* w_k    = (const float*)d_in[3];
    const float* conv_w = (const float*)d_in[4];
    const float* conv_b = (const float*)d_in[5];
    float* out = (float*)d_out;
    float* ws  = (float*)d_ws;    // needs 30*514*516*4 B = 31.8 MB

    const int nblk = NPIX / 256;  // 1024
    k1_pointwise<<<nblk, 256, 0, stream>>>(obs, P, u_k, w_k, ws);
    dim3 g2(nblk, 5);             // 5120 blocks: 80 waves/CU of supply
    k2_conv_roles<<<g2, 256, 0, stream>>>(ws, conv_w, conv_b, out);
}